// Round 7
// baseline (265.017 us; speedup 1.0000x reference)
//
#include <hip/hip_runtime.h>
#include <hip/hip_bf16.h>

typedef __attribute__((ext_vector_type(8))) short bf16x8;
typedef __attribute__((ext_vector_type(4))) float f32x4;
typedef __attribute__((ext_vector_type(8))) unsigned short u16x8;

#define M_DIM 4096
#define N_DIM 1024
#define IN_F  1024
#define K_DIM 12288   // IN_F * 12  (11 spline slots + 1 residual slot)
#define KS4   4
#define KPART (K_DIM / KS4)    // 3072
#define NC    (KPART / 32)     // 96 chunks of 32 k

__device__ __forceinline__ unsigned short f2b(float v) {
  __hip_bfloat16 h = __float2bfloat16(v);
  return *reinterpret_cast<unsigned short*>(&h);
}

__device__ __forceinline__ float fast_tanh(float x) {
  float e = __expf(2.0f * x);
  return 1.0f - 2.0f / (e + 1.0f);
}

// Uniform cubic B-spline, grid = linspace(-1.75, 1.75, 15), h = 0.25.
__device__ __forceinline__ void spline12(float xv, float* w) {
  float t  = fast_tanh(xv);
  float tf = (t + 1.75f) * 4.0f;
  int j = (int)tf;
  j = j < 3 ? 3 : (j > 10 ? 10 : j);
  float u  = tf - (float)j;
  float um = 1.0f - u;
  float u2 = u * u;
  float w0 = um * um * um * (1.0f / 6.0f);
  float w1 = (0.5f * u - 1.0f) * u2 + (2.0f / 3.0f);
  float w2 = ((-0.5f * u + 0.5f) * u + 0.5f) * u + (1.0f / 6.0f);
  float w3 = u * u2 * (1.0f / 6.0f);
  int base = j - 3;
  #pragma unroll
  for (int s = 0; s < 11; ++s) {
    int r = s - base;
    w[s] = (r == 0) ? w0 : (r == 1) ? w1 : (r == 2) ? w2 : (r == 3) ? w3 : 0.0f;
  }
  w[11] = xv;
}

// ---------------- Pass 1b: A[b][i*12+n] bf16, LDS-transposed coalesced stores ----------------
__global__ __launch_bounds__(256) void bases_kernel(const float* __restrict__ x,
                                                    unsigned short* __restrict__ A) {
  __shared__ unsigned short sb[256 * 24];
  const int tid = threadIdx.x;
  int e0 = blockIdx.x * 512 + tid * 2;
  float2 xv = *(const float2*)(x + e0);
  float w0[12], w1[12];
  spline12(xv.x, w0);
  spline12(xv.y, w1);
  #pragma unroll
  for (int s = 0; s < 12; ++s) { sb[tid * 24 + s] = f2b(w0[s]); sb[tid * 24 + 12 + s] = f2b(w1[s]); }
  __syncthreads();
  u16x8* dst = (u16x8*)(A + (size_t)blockIdx.x * 512 * 12);
  const u16x8* src = (const u16x8*)sb;
  #pragma unroll
  for (int k = 0; k < 3; ++k) dst[tid + k * 256] = src[tid + k * 256];
}

// ---------------- Pass 1a: Bt[o][i*12+n] bf16 (coalesced transpose, padded LDS) ----------------
__global__ __launch_bounds__(256) void repack_kernel(const float* __restrict__ coeffs,
                                                     const float* __restrict__ W,
                                                     unsigned short* __restrict__ Bt) {
  __shared__ float lc[64 * 180];
  __shared__ float lw[64 * 20];
  const int o0 = blockIdx.x * 16;
  const int i0 = blockIdx.y * 64;
  const int tid = threadIdx.x;
  #pragma unroll
  for (int it = 0; it < 11; ++it) {
    int v = it * 256 + tid;
    int i = v / 44, c = v - i * 44;
    f32x4 d = *(const f32x4*)(coeffs + ((size_t)(i0 + i) * 1024 + o0) * 11 + c * 4);
    *(f32x4*)(lc + i * 180 + c * 4) = d;
  }
  #pragma unroll
  for (int it = 0; it < 4; ++it) {
    int e = it * 256 + tid;
    int i = e >> 4, ol = e & 15;
    lw[i * 20 + ol] = W[(size_t)(i0 + i) * 1024 + o0 + ol];
  }
  __syncthreads();
  #pragma unroll
  for (int it = 0; it < 6; ++it) {
    int v = it * 256 + tid;
    int ol = v / 96, c = v - ol * 96;
    unsigned short h[8];
    #pragma unroll
    for (int s = 0; s < 8; ++s) {
      int g = c * 8 + s;
      int i = g / 12, n = g - i * 12;
      float val = (n < 11) ? lc[i * 180 + ol * 11 + n] : lw[i * 20 + ol];
      h[s] = f2b(val);
    }
    *(u16x8*)(Bt + (size_t)(o0 + ol) * K_DIM + (size_t)i0 * 12 + c * 8) =
        (u16x8){h[0], h[1], h[2], h[3], h[4], h[5], h[6], h[7]};
  }
}

// ---------------- Pass 2: split-K GEMM, 256x128 tile, 3-deep 32-k chunk ring ----------------
// C[4096,1024] += A*Bt^T. 4 waves (2m x 2n, wave-tile 128x64), 2 blocks/CU, LDS 72 KB.
// Region = A[256x32] (16KB) + B[128x32] (8KB) = 24KB; ring of 3; vmcnt(12) steady gate.
// Pair-row swizzle: row-pair rp stride 128B, 16B-col c' = ((r&1)*4 + c2) ^ (rp&7).
__device__ __forceinline__ void async16(const void* g, void* l) {
  __builtin_amdgcn_global_load_lds(
      (const __attribute__((address_space(1))) void*)g,
      (__attribute__((address_space(3))) void*)l, 16, 0, 0);
}

#define REG_SZ 24576
#define B_OFF  16384

__global__ __launch_bounds__(256, 2) void gemm_kernel(const unsigned short* __restrict__ A,
                                                      const unsigned short* __restrict__ Bt,
                                                      float* __restrict__ out) {
  __shared__ __align__(16) unsigned short lds[36864];   // 72 KB
  char* lp = (char*)lds;

  const int tid  = threadIdx.x;
  const int lane = tid & 63;
  const int wid  = tid >> 6;          // 0..3
  const int wm   = wid >> 1, wn = wid & 1;   // wave-tile 128x64

  // A-exclusive XCD map: 512 blocks; xcd owns bm pair {2*xcd, 2*xcd+1}
  const int blk = blockIdx.x;          // 0..511
  const int xcd = blk & 7;
  const int idx = blk >> 3;            // 0..63
  const int bm  = xcd * 2 + (idx & 1); // 0..15
  const int rst = idx >> 1;            // 0..31
  const int bn  = rst & 7;             // 0..7
  const int ks  = rst >> 3;            // 0..3
  const size_t m0 = (size_t)bm * 256;
  const size_t n0 = (size_t)bn * 128;
  const size_t ksbyte = (size_t)ks * KPART * 2;

  // staging: 6 chunks16B/thread: q=0..3 -> A (1024 slots), q=4,5 -> B (512 slots).
  // slot g: rp = g>>3, c' = g&7; logical c = c' ^ (rp&7); row = 2*rp + (c>>2); k16 = c&3.
  const char* src[6]; int ldst[6];
  #pragma unroll
  for (int q = 0; q < 6; ++q) {
    if (q < 4) {
      int g  = q * 256 + tid;          // 0..1023
      int rp = g >> 3, cp = g & 7;
      int c  = cp ^ (rp & 7);
      int row = (rp << 1) | (c >> 2);
      src[q]  = (const char*)A + ((m0 + row) * (size_t)K_DIM) * 2 + ksbyte + (c & 3) * 16;
      ldst[q] = g * 16;
    } else {
      int g  = (q - 4) * 256 + tid;    // 0..511
      int rp = g >> 3, cp = g & 7;
      int c  = cp ^ (rp & 7);
      int row = (rp << 1) | (c >> 2);
      src[q]  = (const char*)Bt + ((n0 + row) * (size_t)K_DIM) * 2 + ksbyte + (c & 3) * 16;
      ldst[q] = B_OFF + g * 16;
    }
  }

  auto stage = [&](int reg, int chunk) {
    size_t kb = (size_t)chunk * 64;    // 32 k = 64 B per row
    char* rb = lp + reg * REG_SZ;
    #pragma unroll
    for (int q = 0; q < 6; ++q) async16(src[q] + kb, rb + ldst[q]);
  };

  // ds_read offsets (pair-row swizzle), constant over loop
  const int c2 = lane >> 4;
  int offA[8], offB[4];
  #pragma unroll
  for (int m = 0; m < 8; ++m) {
    int r  = wm * 128 + m * 16 + (lane & 15);
    int rp = r >> 1;
    int cp = (((r & 1) << 2) | c2) ^ (rp & 7);
    offA[m] = rp * 128 + cp * 16;
  }
  #pragma unroll
  for (int n = 0; n < 4; ++n) {
    int r  = wn * 64 + n * 16 + (lane & 15);
    int rp = r >> 1;
    int cp = (((r & 1) << 2) | c2) ^ (rp & 7);
    offB[n] = B_OFF + rp * 128 + cp * 16;
  }

  f32x4 acc[8][4];
  #pragma unroll
  for (int m = 0; m < 8; ++m)
    #pragma unroll
    for (int n = 0; n < 4; ++n) acc[m][n] = (f32x4){0.f, 0.f, 0.f, 0.f};

  stage(0, 0);
  stage(1, 1);
  stage(2, 2);

  int reg = 0;
  for (int c = 0; c < NC; ++c) {
    // gate: chunk c landed; chunks c+1, c+2 (12 loads) stay in flight
    if (c < NC - 2)       asm volatile("s_waitcnt vmcnt(12)" ::: "memory");
    else if (c == NC - 2) asm volatile("s_waitcnt vmcnt(6)"  ::: "memory");
    else                  asm volatile("s_waitcnt vmcnt(0)"  ::: "memory");
    __builtin_amdgcn_s_barrier();
    __builtin_amdgcn_sched_barrier(0);
    asm volatile("" ::: "memory");

    char* rb = lp + reg * REG_SZ;
    __builtin_amdgcn_s_setprio(1);
    {
      bf16x8 a[8], b[4];
      #pragma unroll
      for (int m = 0; m < 8; ++m) a[m] = *(const bf16x8*)(rb + offA[m]);
      #pragma unroll
      for (int n = 0; n < 4; ++n) b[n] = *(const bf16x8*)(rb + offB[n]);
      #pragma unroll
      for (int m = 0; m < 8; ++m)
        #pragma unroll
        for (int n = 0; n < 4; ++n)
          acc[m][n] = __builtin_amdgcn_mfma_f32_16x16x32_bf16(a[m], b[n], acc[m][n], 0, 0, 0);
    }
    __builtin_amdgcn_s_setprio(0);

    asm volatile("" ::: "memory");
    __builtin_amdgcn_sched_barrier(0);
    __builtin_amdgcn_s_barrier();       // all waves done reading region

    if (c + 3 < NC) stage(reg, c + 3);  // restage freed region
    reg = (reg == 2) ? 0 : reg + 1;
  }

  const int lr = (lane >> 4) * 4;   // C/D: col=lane&15, row=(lane>>4)*4+j
  const int lc = lane & 15;
  #pragma unroll
  for (int m = 0; m < 8; ++m)
    #pragma unroll
    for (int n = 0; n < 4; ++n)
      #pragma unroll
      for (int j = 0; j < 4; ++j)
        atomicAdd(&out[(m0 + wm * 128 + m * 16 + lr + j) * N_DIM + n0 + wn * 64 + n * 16 + lc],
                  acc[m][n][j]);
}

// ---------------- Fallback (correctness insurance if ws too small) ----------------
__global__ __launch_bounds__(256) void fallback_kernel(const float* __restrict__ x,
                                                       const float* __restrict__ coeffs,
                                                       const float* __restrict__ W,
                                                       float* __restrict__ out) {
  __shared__ float bas[16][64][12];
  const int o0 = blockIdx.x * 64;
  const int b0 = blockIdx.y * 16;
  const int tid = threadIdx.x;
  const int o = tid & 63, bg = tid >> 6;
  float acc[4] = {0.f, 0.f, 0.f, 0.f};
  for (int ic = 0; ic < 16; ++ic) {
    __syncthreads();
    #pragma unroll
    for (int p = 0; p < 4; ++p) {
      int pp = tid + p * 256;
      int bb = pp >> 6, il = pp & 63;
      float w[12];
      spline12(x[(size_t)(b0 + bb) * 1024 + ic * 64 + il], w);
      #pragma unroll
      for (int n = 0; n < 12; ++n) bas[bb][il][n] = w[n];
    }
    __syncthreads();
    for (int il = 0; il < 64; ++il) {
      int gi = ic * 64 + il;
      const float* cp = coeffs + ((size_t)gi * 1024 + o0 + o) * 11;
      float cf[12];
      #pragma unroll
      for (int n = 0; n < 11; ++n) cf[n] = cp[n];
      cf[11] = W[(size_t)gi * 1024 + o0 + o];
      #pragma unroll
      for (int bb = 0; bb < 4; ++bb) {
        float s = 0.f;
        #pragma unroll
        for (int n = 0; n < 12; ++n) s += bas[bg * 4 + bb][il][n] * cf[n];
        acc[bb] += s;
      }
    }
  }
  #pragma unroll
  for (int bb = 0; bb < 4; ++bb)
    out[(size_t)(b0 + bg * 4 + bb) * 1024 + o0 + o] = acc[bb];
}

extern "C" void kernel_launch(void* const* d_in, const int* in_sizes, int n_in,
                              void* d_out, int out_size, void* d_ws, size_t ws_size,
                              hipStream_t stream) {
  const float* x      = (const float*)d_in[0];   // [4096,1024]
  const float* coeffs = (const float*)d_in[1];   // [1024,1024,11]
  const float* W      = (const float*)d_in[2];   // [1024,1024]
  float* out = (float*)d_out;

  const size_t needA = (size_t)M_DIM * K_DIM * 2;
  const size_t needB = (size_t)N_DIM * K_DIM * 2;

  if (ws_size >= needA + needB) {
    unsigned short* Abuf = (unsigned short*)d_ws;
    unsigned short* Btuf = (unsigned short*)((char*)d_ws + needA);
    hipMemsetAsync(out, 0, (size_t)out_size * sizeof(float), stream);
    bases_kernel<<<dim3(M_DIM * IN_F / 512), dim3(256), 0, stream>>>(x, Abuf);
    repack_kernel<<<dim3(64, 16), dim3(256), 0, stream>>>(coeffs, W, Btuf);
    gemm_kernel<<<dim3(512), dim3(256), 0, stream>>>(Abuf, Btuf, out);
  } else {
    fallback_kernel<<<dim3(16, 256), dim3(256), 0, stream>>>(x, coeffs, W, out);
  }
}